// Round 8
// baseline (97.396 us; speedup 1.0000x reference)
//
#include <hip/hip_runtime.h>

#define HLO 63            // (1024-32)/16+1
#define HFULL 1024
#define GF_EPS 1e-4f
#define LOPLANE (HLO*HLO) // 3969
#define NQ 64             // 16-row strips per image
#define NSTAT 40          // 15 ones-sums + 24 w1-quadrant sums + sum(w1)

// quad-level (4-lane) butterfly add via DPP quad_perm — pure VALU, no DS pipe
template<int CTRL>
__device__ __forceinline__ float dppadd(float v) {
    int r = __builtin_amdgcn_update_dpp(0, __float_as_int(v), CTRL, 0xF, 0xF, false);
    return v + __int_as_float(r);
}

// ---------------- Stage A: half-strip blocks, 2 rows/wave, 12 loads hoisted -
// grid: 8 * 64 * 2 * 4 = 4096 blocks of 256 threads (4 waves).
// block = (b, strip qy, half h = 8 rows, 256-col chunk).
// wave qtr handles rows qy*16 + h*8 + qtr*2 + {0,1}; lane owns 4 cols.
// All 12 float4 loads (2 rows x 6 planes) are issued before any compute ->
// 12 outstanding VMEM ops per wave (r7 had ~6 with serial row iters).
// hs layout: [b][qy][h][NSTAT][64]  (k innermost, coalesced for solve)
__global__ __launch_bounds__(256) void gf_vstats(
    const float* __restrict__ guide, const float* __restrict__ src,
    const float* __restrict__ w1, float* __restrict__ hs)
{
    __shared__ float w1s[1024];          // full 32x32 kernel
    __shared__ float red[4][NSTAT][16];  // per-wave partial sums

    int bid = blockIdx.x;
    int chunk = bid & 3;
    int h     = (bid >> 2) & 1;
    int qy    = (bid >> 3) & 63;
    int b     = bid >> 9;
    int tid   = threadIdx.x;     // 0..255
    int lane  = tid & 63;
    int qtr   = tid >> 6;        // wave index

    reinterpret_cast<float4*>(w1s)[tid] = reinterpret_cast<const float4*>(w1)[tid];
    __syncthreads();

    const size_t plane = (size_t)HFULL * HFULL;
    int wrow0 = h * 8 + qtr * 2;          // within-strip row of this wave's row 0
    const size_t rowoff = (size_t)(qy * 16 + wrow0) * HFULL + chunk * 256 + lane * 4;
    const float* g0 = guide + (size_t)b * 3 * plane + rowoff;
    const float* s0 = src   + (size_t)b * 3 * plane + rowoff;

    int xq = lane & 3;                    // quad position -> xin base = 4*xq

    // ---- issue all 12 independent loads up front ----
    float4 gr0 = *reinterpret_cast<const float4*>(g0);
    float4 gr1 = *reinterpret_cast<const float4*>(g0 + HFULL);
    float4 gg0 = *reinterpret_cast<const float4*>(g0 + plane);
    float4 gg1 = *reinterpret_cast<const float4*>(g0 + plane + HFULL);
    float4 gb0 = *reinterpret_cast<const float4*>(g0 + 2 * plane);
    float4 gb1 = *reinterpret_cast<const float4*>(g0 + 2 * plane + HFULL);
    float4 pr0 = *reinterpret_cast<const float4*>(s0);
    float4 pr1 = *reinterpret_cast<const float4*>(s0 + HFULL);
    float4 pg0 = *reinterpret_cast<const float4*>(s0 + plane);
    float4 pg1 = *reinterpret_cast<const float4*>(s0 + plane + HFULL);
    float4 pb0 = *reinterpret_cast<const float4*>(s0 + 2 * plane);
    float4 pb1 = *reinterpret_cast<const float4*>(s0 + 2 * plane + HFULL);

    float acc[NSTAT];
#pragma unroll
    for (int i = 0; i < NSTAT; i++) acc[i] = 0.f;

#pragma unroll
    for (int r = 0; r < 2; ++r) {
        const float* grf = reinterpret_cast<const float*>(r ? &gr1 : &gr0);
        const float* ggf = reinterpret_cast<const float*>(r ? &gg1 : &gg0);
        const float* gbf = reinterpret_cast<const float*>(r ? &gb1 : &gb0);
        const float* prf = reinterpret_cast<const float*>(r ? &pr1 : &pr0);
        const float* pgf = reinterpret_cast<const float*>(r ? &pg1 : &pg0);
        const float* pbf = reinterpret_cast<const float*>(r ? &pb1 : &pb0);

        const float* wr = &w1s[(wrow0 + r) * 32 + 4 * xq];
        float4 w00 = *reinterpret_cast<const float4*>(wr);          // band0, left
        float4 w01 = *reinterpret_cast<const float4*>(wr + 16);     // band0, right
        float4 w10 = *reinterpret_cast<const float4*>(wr + 512);    // band1, left
        float4 w11 = *reinterpret_cast<const float4*>(wr + 528);    // band1, right
        const float* w00f = reinterpret_cast<const float*>(&w00);
        const float* w01f = reinterpret_cast<const float*>(&w01);
        const float* w10f = reinterpret_cast<const float*>(&w10);
        const float* w11f = reinterpret_cast<const float*>(&w11);

#pragma unroll
        for (int j = 0; j < 4; ++j) {
            float Gr = grf[j], Gg = ggf[j], Gb = gbf[j];
            float Pr = prf[j], Pg = pgf[j], Pb = pbf[j];
            float W00 = w00f[j], W01 = w01f[j], W10 = w10f[j], W11 = w11f[j];

            acc[0] += Gr;  acc[1] += Gg;  acc[2] += Gb;
            acc[3] += Pr;  acc[4] += Pg;  acc[5] += Pb;
            acc[6]  += Gr * Pr;  acc[7]  += Gr * Pg;  acc[8]  += Gr * Pb;
            acc[9]  += Gg * Pr;  acc[10] += Gg * Pg;  acc[11] += Gg * Pb;
            acc[12] += Gb * Pr;  acc[13] += Gb * Pg;  acc[14] += Gb * Pb;

            float RR = Gr * Gr, RG = Gr * Gg, RB = Gr * Gb;
            float GG = Gg * Gg, GB = Gg * Gb, BB = Gb * Gb;
            acc[15] += W00 * RR;  acc[16] += W01 * RR;  acc[17] += W10 * RR;  acc[18] += W11 * RR;
            acc[19] += W00 * RG;  acc[20] += W01 * RG;  acc[21] += W10 * RG;  acc[22] += W11 * RG;
            acc[23] += W00 * RB;  acc[24] += W01 * RB;  acc[25] += W10 * RB;  acc[26] += W11 * RB;
            acc[27] += W00 * GG;  acc[28] += W01 * GG;  acc[29] += W10 * GG;  acc[30] += W11 * GG;
            acc[31] += W00 * GB;  acc[32] += W01 * GB;  acc[33] += W10 * GB;  acc[34] += W11 * GB;
            acc[35] += W00 * BB;  acc[36] += W01 * BB;  acc[37] += W10 * BB;  acc[38] += W11 * BB;
            acc[39] += (W00 + W01) + (W10 + W11);
        }
    }

    // reduce across the 4 lanes of each quad (one 16-col group)
#pragma unroll
    for (int i = 0; i < NSTAT; i++) {
        acc[i] = dppadd<0xB1>(acc[i]);   // quad_perm [1,0,3,2]
        acc[i] = dppadd<0x4E>(acc[i]);   // quad_perm [2,3,0,1]
    }

    if ((lane & 3) == 0) {
        int k16 = lane >> 2;
#pragma unroll
        for (int i = 0; i < NSTAT; i++)
            red[qtr][i][k16] = acc[i];
    }
    __syncthreads();

    // sum the 4 waves -> half-strip stats, write hs
    for (int i = tid; i < NSTAT * 16; i += 256) {
        int stat = i >> 4, k16 = i & 15;
        float sum = red[0][stat][k16] + red[1][stat][k16]
                  + red[2][stat][k16] + red[3][stat][k16];
        hs[(((size_t)(b * NQ + qy) * 2 + h) * NSTAT + stat) * 64 + chunk * 16 + k16] = sum;
    }
}

// ---------------- Stage C: assemble windows + 3x3 inverse -> A,b planes -----
__global__ __launch_bounds__(256) void gf_solve(
    const float* __restrict__ hs, float* __restrict__ ab)
{
    int idx = blockIdx.x * 256 + threadIdx.x;
    if (idx >= 8 * LOPLANE) return;
    int lx = idx % HLO;
    int t  = idx / HLO;
    int ly = t % HLO;
    int b  = t / HLO;

    const float* t0 = hs + ((size_t)(b * NQ + ly) * 2) * NSTAT * 64;      // strip ly, half 0
    const float* t1 = t0 + (size_t)NSTAT * 64;                            // strip ly, half 1
    const float* u0 = hs + ((size_t)(b * NQ + ly + 1) * 2) * NSTAT * 64;  // strip ly+1, half 0
    const float* u1 = u0 + (size_t)NSTAT * 64;

    float s[15];
#pragma unroll
    for (int i = 0; i < 15; i++) {
        int o = i * 64 + lx;
        s[i] = ((t0[o] + t1[o]) + (t0[o + 1] + t1[o + 1]))
             + ((u0[o] + u1[o]) + (u0[o + 1] + u1[o + 1]));
    }

    float v[6];
#pragma unroll
    for (int p = 0; p < 6; p++) {
        int bs = 15 + p * 4;
        v[p] = (t0[(bs + 0) * 64 + lx]     + t1[(bs + 0) * 64 + lx])      // top-left
             + (t0[(bs + 1) * 64 + lx + 1] + t1[(bs + 1) * 64 + lx + 1])  // top-right
             + (u0[(bs + 2) * 64 + lx]     + u1[(bs + 2) * 64 + lx])      // bottom-left
             + (u0[(bs + 3) * 64 + lx + 1] + u1[(bs + 3) * 64 + lx + 1]); // bottom-right
    }
    float N = t0[39 * 64 + lx] + t1[39 * 64 + lx];

    float inv_n = 1.f / N;
    float mI[3] = { s[0] * inv_n, s[1] * inv_n, s[2] * inv_n };
    float mp[3] = { s[3] * inv_n, s[4] * inv_n, s[5] * inv_n };

    float cov[3][3];
#pragma unroll
    for (int i = 0; i < 3; i++)
#pragma unroll
        for (int c = 0; c < 3; c++)
            cov[i][c] = s[6 + i * 3 + c] * inv_n - mI[i] * mp[c];

    float v_rr = v[0] * inv_n - mI[0] * mI[0] + GF_EPS;
    float v_rg = v[1] * inv_n - mI[0] * mI[1];
    float v_rb = v[2] * inv_n - mI[0] * mI[2];
    float v_gg = v[3] * inv_n - mI[1] * mI[1] + GF_EPS;
    float v_gb = v[4] * inv_n - mI[1] * mI[2];
    float v_bb = v[5] * inv_n - mI[2] * mI[2] + GF_EPS;

    float det = v_rr * v_gg * v_bb + v_rg * v_gb * v_rb + v_rb * v_rg * v_gb
              - v_rb * v_gg * v_rb - v_rg * v_rg * v_bb - v_rr * v_gb * v_gb;
    float invdet = 1.f / det;

    float i_rr =  (v_gg * v_bb - v_gb * v_gb) * invdet;
    float i_rg = -(v_rg * v_bb - v_rb * v_gb) * invdet;
    float i_rb =  (v_rg * v_gb - v_rb * v_gg) * invdet;
    float i_gg =  (v_rr * v_bb - v_rb * v_rb) * invdet;
    float i_gb = -(v_rr * v_gb - v_rb * v_rg) * invdet;
    float i_bb =  (v_rr * v_gg - v_rg * v_rg) * invdet;

    float inv[3][3] = { { i_rr, i_rg, i_rb },
                        { i_rg, i_gg, i_gb },
                        { i_rb, i_gb, i_bb } };

    float A[3][3];
#pragma unroll
    for (int j = 0; j < 3; j++)
#pragma unroll
        for (int c = 0; c < 3; c++)
            A[j][c] = inv[j][0] * cov[0][c] + inv[j][1] * cov[1][c] + inv[j][2] * cov[2][c];

    float bb_[3];
#pragma unroll
    for (int c = 0; c < 3; c++)
        bb_[c] = mp[c] - A[0][c] * mI[0] - A[1][c] * mI[1] - A[2][c] * mI[2];

    float* outp = ab + (size_t)b * 12 * LOPLANE + ly * HLO + lx;
#pragma unroll
    for (int j = 0; j < 3; j++)
#pragma unroll
        for (int c = 0; c < 3; c++)
            outp[(j * 3 + c) * LOPLANE] = A[j][c];
#pragma unroll
    for (int c = 0; c < 3; c++)
        outp[(9 + c) * LOPLANE] = bb_[c];
}

// ---------------- Stage 3: bilinear upsample of A,b + apply to guide --------
// block = one output row (b, y); y-lerp hoisted to LDS; thread = 4 px float4.
__global__ __launch_bounds__(256) void gf_apply(
    const float* __restrict__ guide, const float* __restrict__ ab,
    float* __restrict__ out)
{
    __shared__ float rl[12][64];   // y-lerped row of each plane (63 used)

    int bid = blockIdx.x;          // 8 * 1024
    int y = bid & 1023;
    int b = bid >> 10;
    int tid = threadIdx.x;

    const float scale = 62.0f / 1023.0f;
    float ty = (float)y * scale;
    int y0 = (int)ty;  if (y0 > 61) y0 = 61;
    float wy = ty - (float)y0;

    const float* abb = ab + (size_t)b * 12 * LOPLANE;
    for (int i = tid; i < 12 * 63; i += 256) {
        int p = i / 63, c = i - p * 63;
        const float* pp = abb + (size_t)p * LOPLANE + y0 * HLO + c;
        rl[p][c] = pp[0] * (1.f - wy) + pp[HLO] * wy;
    }
    __syncthreads();

    int x = 4 * tid;
    float t0 = (float)x * scale;
    int c0 = (int)t0;  if (c0 > 61) c0 = 61;

    bool  sel[4];
    float wx[4];
#pragma unroll
    for (int j = 0; j < 4; ++j) {
        float t = (float)(x + j) * scale;
        int x0 = (int)t;  if (x0 > 61) x0 = 61;
        sel[j] = (x0 > c0);
        wx[j]  = t - (float)x0;
    }

    float Av[12][4];
#pragma unroll
    for (int p = 0; p < 12; ++p) {
        float r0 = rl[p][c0], r1 = rl[p][c0 + 1], r2 = rl[p][c0 + 2];
#pragma unroll
        for (int j = 0; j < 4; ++j) {
            float a  = sel[j] ? r1 : r0;
            float bb = sel[j] ? r2 : r1;
            Av[p][j] = a + (bb - a) * wx[j];
        }
    }

    const size_t plane = (size_t)HFULL * HFULL;
    size_t goff = (size_t)b * 3 * plane + ((size_t)y << 10) + x;
    float4 vgr = *reinterpret_cast<const float4*>(guide + goff);
    float4 vgg = *reinterpret_cast<const float4*>(guide + goff + plane);
    float4 vgb = *reinterpret_cast<const float4*>(guide + goff + 2 * plane);
    const float* grf = reinterpret_cast<const float*>(&vgr);
    const float* ggf = reinterpret_cast<const float*>(&vgg);
    const float* gbf = reinterpret_cast<const float*>(&vgb);

#pragma unroll
    for (int c = 0; c < 3; ++c) {
        float4 o;
        float* of = reinterpret_cast<float*>(&o);
#pragma unroll
        for (int j = 0; j < 4; ++j)
            of[j] = Av[0 + c][j] * grf[j] + Av[3 + c][j] * ggf[j]
                  + Av[6 + c][j] * gbf[j] + Av[9 + c][j];
        *reinterpret_cast<float4*>(out + goff + (size_t)c * plane) = o;
    }
}

extern "C" void kernel_launch(void* const* d_in, const int* in_sizes, int n_in,
                              void* d_out, int out_size, void* d_ws, size_t ws_size,
                              hipStream_t stream) {
    const float* guide = (const float*)d_in[0];
    const float* src   = (const float*)d_in[1];
    const float* w1    = (const float*)d_in[2];
    // d_in[3] = w3 is all-ones; box3 == plain window sum.
    float* out = (float*)d_out;

    float* ab = (float*)d_ws;                         // 1.53 MB
    float* hs = (float*)((char*)d_ws + (2 << 20));    // 10.5 MB: [8][64][2][40][64]

    gf_vstats<<<8 * NQ * 2 * 4, 256, 0, stream>>>(guide, src, w1, hs);

    int nthr = 8 * LOPLANE;
    gf_solve<<<(nthr + 255) / 256, 256, 0, stream>>>(hs, ab);

    gf_apply<<<8 * 1024, 256, 0, stream>>>(guide, ab, out);
}

// Round 9
// 86.607 us; speedup vs baseline: 1.1246x; 1.1246x over previous
//
#include <hip/hip_runtime.h>

#define HLO 63            // (1024-32)/16+1
#define HFULL 1024
#define GF_EPS 1e-4f
#define LOPLANE (HLO*HLO) // 3969
#define NQ 64             // 16-row strips per image
#define NSTAT 40          // 15 ones-sums + 24 w1-quadrant sums + sum(w1)

// quad-level (4-lane) butterfly add via DPP quad_perm — pure VALU, no DS pipe
template<int CTRL>
__device__ __forceinline__ float dppadd(float v) {
    int r = __builtin_amdgcn_update_dpp(0, __float_as_int(v), CTRL, 0xF, 0xF, false);
    return v + __int_as_float(r);
}

// async global->LDS DMA, 16B per lane, no VGPR round-trip.
// LDS dest = wave-uniform base + lane*16; global src is per-lane.
__device__ __forceinline__ void dma16(const float* g, float* l) {
    __builtin_amdgcn_global_load_lds(
        (const __attribute__((address_space(1))) unsigned int*)g,
        (__attribute__((address_space(3))) unsigned int*)l,
        16, 0, 0);
}

// ---------------- Stage A: half-strip blocks, LDS-staged via async DMA ------
// grid: 8 * 64 * 2 * 4 = 4096 blocks of 256 threads (4 waves).
// block = (b, strip qy, half h = 8 rows, 256-col chunk).
// Phase 1: 48 async 1KB DMAs (6 planes x 8 rows), 12 per wave, zero VGPR cost.
// Phase 2: wave wv computes rows wv*2, wv*2+1 from LDS (40-acc VALU as before).
// hs layout: [b][qy][h][NSTAT][64]  (k innermost, halves contiguous per strip)
__global__ __launch_bounds__(256) void gf_vstats(
    const float* __restrict__ guide, const float* __restrict__ src,
    const float* __restrict__ w1, float* __restrict__ hs)
{
    __shared__ float data[6][8][256];    // 48 KB staged half-strip
    __shared__ float w1s[1024];          // 4 KB
    __shared__ float red[4][NSTAT][16];  // 10 KB

    int bid = blockIdx.x;
    int chunk = bid & 3;
    int h     = (bid >> 2) & 1;
    int qy    = (bid >> 3) & 63;
    int b     = bid >> 9;
    int tid   = threadIdx.x;
    int lane  = tid & 63;
    int wv    = tid >> 6;

    reinterpret_cast<float4*>(w1s)[tid] = reinterpret_cast<const float4*>(w1)[tid];

    const size_t plane = (size_t)HFULL * HFULL;
    const float* g0 = guide + (size_t)b * 3 * plane
                    + (size_t)(qy * 16 + h * 8) * HFULL + chunk * 256;
    const float* s0 = src   + (size_t)b * 3 * plane
                    + (size_t)(qy * 16 + h * 8) * HFULL + chunk * 256;

    // ---- Phase 1: issue 12 async DMAs per wave (plane p, row r) ----
#pragma unroll
    for (int ff = 0; ff < 12; ++ff) {
        int f = wv * 12 + ff;
        int p = f >> 3, r = f & 7;
        const float* gp = (p < 3 ? g0 + (size_t)p * plane
                                 : s0 + (size_t)(p - 3) * plane)
                        + (size_t)r * HFULL + lane * 4;
        dma16(gp, &data[p][r][0]);
    }
    __syncthreads();   // drains vmcnt(0) before barrier

    // ---- Phase 2: compute from LDS ----
    int xq = lane & 3;            // quad position -> xin base = 4*xq

    float acc[NSTAT];
#pragma unroll
    for (int i = 0; i < NSTAT; i++) acc[i] = 0.f;

#pragma unroll
    for (int rr = 0; rr < 2; ++rr) {
        int row = wv * 2 + rr;            // row within the 8-row half
        int yin = h * 8 + row;            // row within the 16-row strip
        float4 vgr = *reinterpret_cast<const float4*>(&data[0][row][lane * 4]);
        float4 vgg = *reinterpret_cast<const float4*>(&data[1][row][lane * 4]);
        float4 vgb = *reinterpret_cast<const float4*>(&data[2][row][lane * 4]);
        float4 vpr = *reinterpret_cast<const float4*>(&data[3][row][lane * 4]);
        float4 vpg = *reinterpret_cast<const float4*>(&data[4][row][lane * 4]);
        float4 vpb = *reinterpret_cast<const float4*>(&data[5][row][lane * 4]);

        const float* wr_ = &w1s[yin * 32 + 4 * xq];
        float4 w00 = *reinterpret_cast<const float4*>(wr_);         // band0, left
        float4 w01 = *reinterpret_cast<const float4*>(wr_ + 16);    // band0, right
        float4 w10 = *reinterpret_cast<const float4*>(wr_ + 512);   // band1, left
        float4 w11 = *reinterpret_cast<const float4*>(wr_ + 528);   // band1, right

        const float* grf = reinterpret_cast<const float*>(&vgr);
        const float* ggf = reinterpret_cast<const float*>(&vgg);
        const float* gbf = reinterpret_cast<const float*>(&vgb);
        const float* prf = reinterpret_cast<const float*>(&vpr);
        const float* pgf = reinterpret_cast<const float*>(&vpg);
        const float* pbf = reinterpret_cast<const float*>(&vpb);
        const float* w00f = reinterpret_cast<const float*>(&w00);
        const float* w01f = reinterpret_cast<const float*>(&w01);
        const float* w10f = reinterpret_cast<const float*>(&w10);
        const float* w11f = reinterpret_cast<const float*>(&w11);

#pragma unroll
        for (int j = 0; j < 4; ++j) {
            float Gr = grf[j], Gg = ggf[j], Gb = gbf[j];
            float Pr = prf[j], Pg = pgf[j], Pb = pbf[j];
            float W00 = w00f[j], W01 = w01f[j], W10 = w10f[j], W11 = w11f[j];

            acc[0] += Gr;  acc[1] += Gg;  acc[2] += Gb;
            acc[3] += Pr;  acc[4] += Pg;  acc[5] += Pb;
            acc[6]  += Gr * Pr;  acc[7]  += Gr * Pg;  acc[8]  += Gr * Pb;
            acc[9]  += Gg * Pr;  acc[10] += Gg * Pg;  acc[11] += Gg * Pb;
            acc[12] += Gb * Pr;  acc[13] += Gb * Pg;  acc[14] += Gb * Pb;

            float RR = Gr * Gr, RG = Gr * Gg, RB = Gr * Gb;
            float GG = Gg * Gg, GB = Gg * Gb, BB = Gb * Gb;
            acc[15] += W00 * RR;  acc[16] += W01 * RR;  acc[17] += W10 * RR;  acc[18] += W11 * RR;
            acc[19] += W00 * RG;  acc[20] += W01 * RG;  acc[21] += W10 * RG;  acc[22] += W11 * RG;
            acc[23] += W00 * RB;  acc[24] += W01 * RB;  acc[25] += W10 * RB;  acc[26] += W11 * RB;
            acc[27] += W00 * GG;  acc[28] += W01 * GG;  acc[29] += W10 * GG;  acc[30] += W11 * GG;
            acc[31] += W00 * GB;  acc[32] += W01 * GB;  acc[33] += W10 * GB;  acc[34] += W11 * GB;
            acc[35] += W00 * BB;  acc[36] += W01 * BB;  acc[37] += W10 * BB;  acc[38] += W11 * BB;
            acc[39] += (W00 + W01) + (W10 + W11);
        }
    }

    // reduce across the 4 lanes of each quad (one 16-col group)
#pragma unroll
    for (int i = 0; i < NSTAT; i++) {
        acc[i] = dppadd<0xB1>(acc[i]);   // quad_perm [1,0,3,2]
        acc[i] = dppadd<0x4E>(acc[i]);   // quad_perm [2,3,0,1]
    }

    if ((lane & 3) == 0) {
        int k16 = lane >> 2;
#pragma unroll
        for (int i = 0; i < NSTAT; i++)
            red[wv][i][k16] = acc[i];
    }
    __syncthreads();

    // sum the 4 waves -> half-strip stats, write hs
    for (int i = tid; i < NSTAT * 16; i += 256) {
        int stat = i >> 4, k16 = i & 15;
        float sum = red[0][stat][k16] + red[1][stat][k16]
                  + red[2][stat][k16] + red[3][stat][k16];
        hs[(((size_t)(b * NQ + qy) * 2 + h) * NSTAT + stat) * 64 + chunk * 16 + k16] = sum;
    }
}

// ---------------- Stage C: LDS-staged window assembly + 3x3 inverse ---------
// block = (b, ly): 504 blocks of 256 threads. Copy the 4 half-records (40KB)
// into LDS coalesced, then 63 threads compute the ly-row of windows.
__global__ __launch_bounds__(256) void gf_solve(
    const float* __restrict__ hs, float* __restrict__ ab)
{
    __shared__ float hl[4][NSTAT][64];   // t0,t1,u0,u1  (40 KB)

    int bid = blockIdx.x;
    int ly = bid % HLO;
    int b  = bid / HLO;
    int tid = threadIdx.x;

    const float4* srcA = reinterpret_cast<const float4*>(
        hs + ((size_t)(b * NQ + ly) * 2) * NSTAT * 64);        // strip ly, both halves
    const float4* srcB = reinterpret_cast<const float4*>(
        hs + ((size_t)(b * NQ + ly + 1) * 2) * NSTAT * 64);    // strip ly+1, both halves
    float4* dstA = reinterpret_cast<float4*>(&hl[0][0][0]);
    float4* dstB = reinterpret_cast<float4*>(&hl[2][0][0]);

#pragma unroll
    for (int i = 0; i < 5; ++i) {
        int o = i * 256 + tid;           // 1280 float4 per region
        dstA[o] = srcA[o];
        dstB[o] = srcB[o];
    }
    __syncthreads();

    if (tid >= HLO) return;
    int lx = tid;

    float s[15];
#pragma unroll
    for (int i = 0; i < 15; i++) {
        s[i] = ((hl[0][i][lx] + hl[1][i][lx]) + (hl[0][i][lx + 1] + hl[1][i][lx + 1]))
             + ((hl[2][i][lx] + hl[3][i][lx]) + (hl[2][i][lx + 1] + hl[3][i][lx + 1]));
    }

    float v[6];
#pragma unroll
    for (int p = 0; p < 6; p++) {
        int bs = 15 + p * 4;
        v[p] = (hl[0][bs + 0][lx]     + hl[1][bs + 0][lx])      // top-left
             + (hl[0][bs + 1][lx + 1] + hl[1][bs + 1][lx + 1])  // top-right
             + (hl[2][bs + 2][lx]     + hl[3][bs + 2][lx])      // bottom-left
             + (hl[2][bs + 3][lx + 1] + hl[3][bs + 3][lx + 1]); // bottom-right
    }
    float N = hl[0][39][lx] + hl[1][39][lx];

    float inv_n = 1.f / N;
    float mI[3] = { s[0] * inv_n, s[1] * inv_n, s[2] * inv_n };
    float mp[3] = { s[3] * inv_n, s[4] * inv_n, s[5] * inv_n };

    float cov[3][3];
#pragma unroll
    for (int i = 0; i < 3; i++)
#pragma unroll
        for (int c = 0; c < 3; c++)
            cov[i][c] = s[6 + i * 3 + c] * inv_n - mI[i] * mp[c];

    float v_rr = v[0] * inv_n - mI[0] * mI[0] + GF_EPS;
    float v_rg = v[1] * inv_n - mI[0] * mI[1];
    float v_rb = v[2] * inv_n - mI[0] * mI[2];
    float v_gg = v[3] * inv_n - mI[1] * mI[1] + GF_EPS;
    float v_gb = v[4] * inv_n - mI[1] * mI[2];
    float v_bb = v[5] * inv_n - mI[2] * mI[2] + GF_EPS;

    float det = v_rr * v_gg * v_bb + v_rg * v_gb * v_rb + v_rb * v_rg * v_gb
              - v_rb * v_gg * v_rb - v_rg * v_rg * v_bb - v_rr * v_gb * v_gb;
    float invdet = 1.f / det;

    float i_rr =  (v_gg * v_bb - v_gb * v_gb) * invdet;
    float i_rg = -(v_rg * v_bb - v_rb * v_gb) * invdet;
    float i_rb =  (v_rg * v_gb - v_rb * v_gg) * invdet;
    float i_gg =  (v_rr * v_bb - v_rb * v_rb) * invdet;
    float i_gb = -(v_rr * v_gb - v_rb * v_rg) * invdet;
    float i_bb =  (v_rr * v_gg - v_rg * v_rg) * invdet;

    float inv[3][3] = { { i_rr, i_rg, i_rb },
                        { i_rg, i_gg, i_gb },
                        { i_rb, i_gb, i_bb } };

    float A[3][3];
#pragma unroll
    for (int j = 0; j < 3; j++)
#pragma unroll
        for (int c = 0; c < 3; c++)
            A[j][c] = inv[j][0] * cov[0][c] + inv[j][1] * cov[1][c] + inv[j][2] * cov[2][c];

    float bb_[3];
#pragma unroll
    for (int c = 0; c < 3; c++)
        bb_[c] = mp[c] - A[0][c] * mI[0] - A[1][c] * mI[1] - A[2][c] * mI[2];

    float* outp = ab + (size_t)b * 12 * LOPLANE + ly * HLO + lx;
#pragma unroll
    for (int j = 0; j < 3; j++)
#pragma unroll
        for (int c = 0; c < 3; c++)
            outp[(j * 3 + c) * LOPLANE] = A[j][c];
#pragma unroll
    for (int c = 0; c < 3; c++)
        outp[(9 + c) * LOPLANE] = bb_[c];
}

// ---------------- Stage 3: bilinear upsample of A,b + apply to guide --------
// block = one output row (b, y); y-lerp hoisted to LDS; thread = 4 px float4.
__global__ __launch_bounds__(256) void gf_apply(
    const float* __restrict__ guide, const float* __restrict__ ab,
    float* __restrict__ out)
{
    __shared__ float rl[12][64];   // y-lerped row of each plane (63 used)

    int bid = blockIdx.x;          // 8 * 1024
    int y = bid & 1023;
    int b = bid >> 10;
    int tid = threadIdx.x;

    const float scale = 62.0f / 1023.0f;
    float ty = (float)y * scale;
    int y0 = (int)ty;  if (y0 > 61) y0 = 61;
    float wy = ty - (float)y0;

    const float* abb = ab + (size_t)b * 12 * LOPLANE;
    for (int i = tid; i < 12 * 63; i += 256) {
        int p = i / 63, c = i - p * 63;
        const float* pp = abb + (size_t)p * LOPLANE + y0 * HLO + c;
        rl[p][c] = pp[0] * (1.f - wy) + pp[HLO] * wy;
    }
    __syncthreads();

    int x = 4 * tid;
    float t0 = (float)x * scale;
    int c0 = (int)t0;  if (c0 > 61) c0 = 61;

    bool  sel[4];
    float wx[4];
#pragma unroll
    for (int j = 0; j < 4; ++j) {
        float t = (float)(x + j) * scale;
        int x0 = (int)t;  if (x0 > 61) x0 = 61;
        sel[j] = (x0 > c0);
        wx[j]  = t - (float)x0;
    }

    float Av[12][4];
#pragma unroll
    for (int p = 0; p < 12; ++p) {
        float r0 = rl[p][c0], r1 = rl[p][c0 + 1], r2 = rl[p][c0 + 2];
#pragma unroll
        for (int j = 0; j < 4; ++j) {
            float a  = sel[j] ? r1 : r0;
            float bb = sel[j] ? r2 : r1;
            Av[p][j] = a + (bb - a) * wx[j];
        }
    }

    const size_t plane = (size_t)HFULL * HFULL;
    size_t goff = (size_t)b * 3 * plane + ((size_t)y << 10) + x;
    float4 vgr = *reinterpret_cast<const float4*>(guide + goff);
    float4 vgg = *reinterpret_cast<const float4*>(guide + goff + plane);
    float4 vgb = *reinterpret_cast<const float4*>(guide + goff + 2 * plane);
    const float* grf = reinterpret_cast<const float*>(&vgr);
    const float* ggf = reinterpret_cast<const float*>(&vgg);
    const float* gbf = reinterpret_cast<const float*>(&vgb);

#pragma unroll
    for (int c = 0; c < 3; ++c) {
        float4 o;
        float* of = reinterpret_cast<float*>(&o);
#pragma unroll
        for (int j = 0; j < 4; ++j)
            of[j] = Av[0 + c][j] * grf[j] + Av[3 + c][j] * ggf[j]
                  + Av[6 + c][j] * gbf[j] + Av[9 + c][j];
        *reinterpret_cast<float4*>(out + goff + (size_t)c * plane) = o;
    }
}

extern "C" void kernel_launch(void* const* d_in, const int* in_sizes, int n_in,
                              void* d_out, int out_size, void* d_ws, size_t ws_size,
                              hipStream_t stream) {
    const float* guide = (const float*)d_in[0];
    const float* src   = (const float*)d_in[1];
    const float* w1    = (const float*)d_in[2];
    // d_in[3] = w3 is all-ones; box3 == plain window sum.
    float* out = (float*)d_out;

    float* ab = (float*)d_ws;                         // 1.53 MB
    float* hs = (float*)((char*)d_ws + (2 << 20));    // 10.5 MB: [8][64][2][40][64]

    gf_vstats<<<8 * NQ * 2 * 4, 256, 0, stream>>>(guide, src, w1, hs);

    gf_solve<<<8 * HLO, 256, 0, stream>>>(hs, ab);

    gf_apply<<<8 * 1024, 256, 0, stream>>>(guide, ab, out);
}

// Round 10
// 86.516 us; speedup vs baseline: 1.1258x; 1.0011x over previous
//
#include <hip/hip_runtime.h>

#define HLO 63            // (1024-32)/16+1
#define HFULL 1024
#define GF_EPS 1e-4f
#define LOPLANE (HLO*HLO) // 3969
#define NQ 64             // 16-row strips per image
#define NSTAT 40          // 15 ones-sums + 24 w1-quadrant sums + sum(w1)

// quad-level (4-lane) butterfly add via DPP quad_perm — pure VALU, no DS pipe
template<int CTRL>
__device__ __forceinline__ float dppadd(float v) {
    int r = __builtin_amdgcn_update_dpp(0, __float_as_int(v), CTRL, 0xF, 0xF, false);
    return v + __int_as_float(r);
}

// ---------------- Stage A: apply-style churn: 1 float4 per thread -----------
// grid: 8 * 64 * 16 = 8192 blocks of 256 threads (4 waves).
// block = (b, strip qy, 64-col group cg). Wave wv covers rows wv*4..+3 x 64 cols.
// lane = (c4<<2)|r: r = row in band, c4 = float4 col index (0..15).
// Exactly ONE generation of loads per thread (6 plane float4 + 4 w1 taps from
// global, L1-resident), no staging barrier, tiny LDS -> max block churn.
// hs layout: [b][qy][NSTAT][64]  (strip-level, k innermost)
__global__ __launch_bounds__(256) void gf_vstats(
    const float* __restrict__ guide, const float* __restrict__ src,
    const float* __restrict__ w1, float* __restrict__ hs)
{
    __shared__ float red[4][NSTAT][4];   // wave, stat, group  (2.6 KB)

    int bid = blockIdx.x;
    int cg = bid & 15;
    int qy = (bid >> 4) & 63;
    int b  = bid >> 10;
    int tid = threadIdx.x;
    int lane = tid & 63;
    int wv   = tid >> 6;

    int r   = lane & 3;          // row within wave's 4-row band
    int c4  = lane >> 2;         // float4 index within 64 cols (0..15)
    int xin = (c4 & 3) * 4;      // col offset within this 16-col k-group
    int yin = wv * 4 + r;        // row within the 16-row strip

    const size_t plane = (size_t)HFULL * HFULL;
    const float* g0 = guide + (size_t)b * 3 * plane
                    + (size_t)(qy * 16 + yin) * HFULL + cg * 64 + c4 * 4;
    const float* s0 = src   + (size_t)b * 3 * plane
                    + (size_t)(qy * 16 + yin) * HFULL + cg * 64 + c4 * 4;

    // ---- one generation of loads: 6 data + 4 w taps ----
    float4 vgr = *reinterpret_cast<const float4*>(g0);
    float4 vgg = *reinterpret_cast<const float4*>(g0 + plane);
    float4 vgb = *reinterpret_cast<const float4*>(g0 + 2 * plane);
    float4 vpr = *reinterpret_cast<const float4*>(s0);
    float4 vpg = *reinterpret_cast<const float4*>(s0 + plane);
    float4 vpb = *reinterpret_cast<const float4*>(s0 + 2 * plane);
    const float* wb = w1 + yin * 32 + xin;
    float4 w00 = *reinterpret_cast<const float4*>(wb);          // band0, left half
    float4 w01 = *reinterpret_cast<const float4*>(wb + 16);     // band0, right half
    float4 w10 = *reinterpret_cast<const float4*>(wb + 512);    // band1, left half
    float4 w11 = *reinterpret_cast<const float4*>(wb + 528);    // band1, right half

    const float* grf = reinterpret_cast<const float*>(&vgr);
    const float* ggf = reinterpret_cast<const float*>(&vgg);
    const float* gbf = reinterpret_cast<const float*>(&vgb);
    const float* prf = reinterpret_cast<const float*>(&vpr);
    const float* pgf = reinterpret_cast<const float*>(&vpg);
    const float* pbf = reinterpret_cast<const float*>(&vpb);
    const float* w00f = reinterpret_cast<const float*>(&w00);
    const float* w01f = reinterpret_cast<const float*>(&w01);
    const float* w10f = reinterpret_cast<const float*>(&w10);
    const float* w11f = reinterpret_cast<const float*>(&w11);

    float acc[NSTAT];
#pragma unroll
    for (int i = 0; i < NSTAT; i++) acc[i] = 0.f;

#pragma unroll
    for (int j = 0; j < 4; ++j) {
        float Gr = grf[j], Gg = ggf[j], Gb = gbf[j];
        float Pr = prf[j], Pg = pgf[j], Pb = pbf[j];
        float W00 = w00f[j], W01 = w01f[j], W10 = w10f[j], W11 = w11f[j];

        acc[0] += Gr;  acc[1] += Gg;  acc[2] += Gb;
        acc[3] += Pr;  acc[4] += Pg;  acc[5] += Pb;
        acc[6]  += Gr * Pr;  acc[7]  += Gr * Pg;  acc[8]  += Gr * Pb;
        acc[9]  += Gg * Pr;  acc[10] += Gg * Pg;  acc[11] += Gg * Pb;
        acc[12] += Gb * Pr;  acc[13] += Gb * Pg;  acc[14] += Gb * Pb;

        float RR = Gr * Gr, RG = Gr * Gg, RB = Gr * Gb;
        float GG = Gg * Gg, GB = Gg * Gb, BB = Gb * Gb;
        acc[15] += W00 * RR;  acc[16] += W01 * RR;  acc[17] += W10 * RR;  acc[18] += W11 * RR;
        acc[19] += W00 * RG;  acc[20] += W01 * RG;  acc[21] += W10 * RG;  acc[22] += W11 * RG;
        acc[23] += W00 * RB;  acc[24] += W01 * RB;  acc[25] += W10 * RB;  acc[26] += W11 * RB;
        acc[27] += W00 * GG;  acc[28] += W01 * GG;  acc[29] += W10 * GG;  acc[30] += W11 * GG;
        acc[31] += W00 * GB;  acc[32] += W01 * GB;  acc[33] += W10 * GB;  acc[34] += W11 * GB;
        acc[35] += W00 * BB;  acc[36] += W01 * BB;  acc[37] += W10 * BB;  acc[38] += W11 * BB;
        acc[39] += (W00 + W01) + (W10 + W11);
    }

    // reduce: rows (lane&3, DPP quads) then col-pieces within k-group (xor 4,8)
#pragma unroll
    for (int i = 0; i < NSTAT; i++) {
        acc[i] = dppadd<0xB1>(acc[i]);       // quad_perm [1,0,3,2]
        acc[i] = dppadd<0x4E>(acc[i]);       // quad_perm [2,3,0,1]
        acc[i] += __shfl_xor(acc[i], 4, 64);
        acc[i] += __shfl_xor(acc[i], 8, 64);
    }

    if ((lane & 15) == 0) {
        int g = lane >> 4;                   // k-group within block (0..3)
#pragma unroll
        for (int i = 0; i < NSTAT; i++)
            red[wv][i][g] = acc[i];
    }
    __syncthreads();

    // sum the 4 waves (16 rows) -> strip stats, write hs
    if (tid < NSTAT * 4) {
        int stat = tid >> 2, g = tid & 3;
        float sum = red[0][stat][g] + red[1][stat][g]
                  + red[2][stat][g] + red[3][stat][g];
        hs[((size_t)(b * NQ + qy) * NSTAT + stat) * 64 + cg * 4 + g] = sum;
    }
}

// ---------------- Stage C: LDS-staged window assembly + 3x3 inverse ---------
// block = (b, ly): 504 blocks. Copy 2 strip records (20KB) into LDS coalesced,
// then 63 threads compute the ly-row of windows.
__global__ __launch_bounds__(256) void gf_solve(
    const float* __restrict__ hs, float* __restrict__ ab)
{
    __shared__ float hl[2][NSTAT][64];   // 20 KB

    int bid = blockIdx.x;
    int ly = bid % HLO;
    int b  = bid / HLO;
    int tid = threadIdx.x;

    const float4* sA = reinterpret_cast<const float4*>(
        hs + (size_t)(b * NQ + ly) * NSTAT * 64);       // strip ly
    const float4* sB = reinterpret_cast<const float4*>(
        hs + (size_t)(b * NQ + ly + 1) * NSTAT * 64);   // strip ly+1
    float4* dA = reinterpret_cast<float4*>(&hl[0][0][0]);
    float4* dB = reinterpret_cast<float4*>(&hl[1][0][0]);

    for (int i = tid; i < NSTAT * 16; i += 256) {       // 640 float4 each
        dA[i] = sA[i];
        dB[i] = sB[i];
    }
    __syncthreads();

    if (tid >= HLO) return;
    int lx = tid;

    float s[15];
#pragma unroll
    for (int i = 0; i < 15; i++)
        s[i] = (hl[0][i][lx] + hl[0][i][lx + 1]) + (hl[1][i][lx] + hl[1][i][lx + 1]);

    float v[6];
#pragma unroll
    for (int p = 0; p < 6; p++) {
        int bs = 15 + p * 4;
        v[p] = hl[0][bs + 0][lx]        // top-left
             + hl[0][bs + 1][lx + 1]    // top-right
             + hl[1][bs + 2][lx]        // bottom-left
             + hl[1][bs + 3][lx + 1];   // bottom-right
    }
    float N = hl[0][39][lx];

    float inv_n = 1.f / N;
    float mI[3] = { s[0] * inv_n, s[1] * inv_n, s[2] * inv_n };
    float mp[3] = { s[3] * inv_n, s[4] * inv_n, s[5] * inv_n };

    float cov[3][3];
#pragma unroll
    for (int i = 0; i < 3; i++)
#pragma unroll
        for (int c = 0; c < 3; c++)
            cov[i][c] = s[6 + i * 3 + c] * inv_n - mI[i] * mp[c];

    float v_rr = v[0] * inv_n - mI[0] * mI[0] + GF_EPS;
    float v_rg = v[1] * inv_n - mI[0] * mI[1];
    float v_rb = v[2] * inv_n - mI[0] * mI[2];
    float v_gg = v[3] * inv_n - mI[1] * mI[1] + GF_EPS;
    float v_gb = v[4] * inv_n - mI[1] * mI[2];
    float v_bb = v[5] * inv_n - mI[2] * mI[2] + GF_EPS;

    float det = v_rr * v_gg * v_bb + v_rg * v_gb * v_rb + v_rb * v_rg * v_gb
              - v_rb * v_gg * v_rb - v_rg * v_rg * v_bb - v_rr * v_gb * v_gb;
    float invdet = 1.f / det;

    float i_rr =  (v_gg * v_bb - v_gb * v_gb) * invdet;
    float i_rg = -(v_rg * v_bb - v_rb * v_gb) * invdet;
    float i_rb =  (v_rg * v_gb - v_rb * v_gg) * invdet;
    float i_gg =  (v_rr * v_bb - v_rb * v_rb) * invdet;
    float i_gb = -(v_rr * v_gb - v_rb * v_rg) * invdet;
    float i_bb =  (v_rr * v_gg - v_rg * v_rg) * invdet;

    float inv[3][3] = { { i_rr, i_rg, i_rb },
                        { i_rg, i_gg, i_gb },
                        { i_rb, i_gb, i_bb } };

    float A[3][3];
#pragma unroll
    for (int j = 0; j < 3; j++)
#pragma unroll
        for (int c = 0; c < 3; c++)
            A[j][c] = inv[j][0] * cov[0][c] + inv[j][1] * cov[1][c] + inv[j][2] * cov[2][c];

    float bb_[3];
#pragma unroll
    for (int c = 0; c < 3; c++)
        bb_[c] = mp[c] - A[0][c] * mI[0] - A[1][c] * mI[1] - A[2][c] * mI[2];

    float* outp = ab + (size_t)b * 12 * LOPLANE + ly * HLO + lx;
#pragma unroll
    for (int j = 0; j < 3; j++)
#pragma unroll
        for (int c = 0; c < 3; c++)
            outp[(j * 3 + c) * LOPLANE] = A[j][c];
#pragma unroll
    for (int c = 0; c < 3; c++)
        outp[(9 + c) * LOPLANE] = bb_[c];
}

// ---------------- Stage 3: bilinear upsample of A,b + apply to guide --------
// block = one output row (b, y); y-lerp hoisted to LDS; thread = 4 px float4.
__global__ __launch_bounds__(256) void gf_apply(
    const float* __restrict__ guide, const float* __restrict__ ab,
    float* __restrict__ out)
{
    __shared__ float rl[12][64];   // y-lerped row of each plane (63 used)

    int bid = blockIdx.x;          // 8 * 1024
    int y = bid & 1023;
    int b = bid >> 10;
    int tid = threadIdx.x;

    const float scale = 62.0f / 1023.0f;
    float ty = (float)y * scale;
    int y0 = (int)ty;  if (y0 > 61) y0 = 61;
    float wy = ty - (float)y0;

    const float* abb = ab + (size_t)b * 12 * LOPLANE;
    for (int i = tid; i < 12 * 63; i += 256) {
        int p = i / 63, c = i - p * 63;
        const float* pp = abb + (size_t)p * LOPLANE + y0 * HLO + c;
        rl[p][c] = pp[0] * (1.f - wy) + pp[HLO] * wy;
    }
    __syncthreads();

    int x = 4 * tid;
    float t0 = (float)x * scale;
    int c0 = (int)t0;  if (c0 > 61) c0 = 61;

    bool  sel[4];
    float wx[4];
#pragma unroll
    for (int j = 0; j < 4; ++j) {
        float t = (float)(x + j) * scale;
        int x0 = (int)t;  if (x0 > 61) x0 = 61;
        sel[j] = (x0 > c0);
        wx[j]  = t - (float)x0;
    }

    float Av[12][4];
#pragma unroll
    for (int p = 0; p < 12; ++p) {
        float r0 = rl[p][c0], r1 = rl[p][c0 + 1], r2 = rl[p][c0 + 2];
#pragma unroll
        for (int j = 0; j < 4; ++j) {
            float a  = sel[j] ? r1 : r0;
            float bb = sel[j] ? r2 : r1;
            Av[p][j] = a + (bb - a) * wx[j];
        }
    }

    const size_t plane = (size_t)HFULL * HFULL;
    size_t goff = (size_t)b * 3 * plane + ((size_t)y << 10) + x;
    float4 vgr = *reinterpret_cast<const float4*>(guide + goff);
    float4 vgg = *reinterpret_cast<const float4*>(guide + goff + plane);
    float4 vgb = *reinterpret_cast<const float4*>(guide + goff + 2 * plane);
    const float* grf = reinterpret_cast<const float*>(&vgr);
    const float* ggf = reinterpret_cast<const float*>(&vgg);
    const float* gbf = reinterpret_cast<const float*>(&vgb);

#pragma unroll
    for (int c = 0; c < 3; ++c) {
        float4 o;
        float* of = reinterpret_cast<float*>(&o);
#pragma unroll
        for (int j = 0; j < 4; ++j)
            of[j] = Av[0 + c][j] * grf[j] + Av[3 + c][j] * ggf[j]
                  + Av[6 + c][j] * gbf[j] + Av[9 + c][j];
        *reinterpret_cast<float4*>(out + goff + (size_t)c * plane) = o;
    }
}

extern "C" void kernel_launch(void* const* d_in, const int* in_sizes, int n_in,
                              void* d_out, int out_size, void* d_ws, size_t ws_size,
                              hipStream_t stream) {
    const float* guide = (const float*)d_in[0];
    const float* src   = (const float*)d_in[1];
    const float* w1    = (const float*)d_in[2];
    // d_in[3] = w3 is all-ones; box3 == plain window sum.
    float* out = (float*)d_out;

    float* ab = (float*)d_ws;                         // 1.53 MB
    float* hs = (float*)((char*)d_ws + (2 << 20));    // 5.25 MB: [8][64][40][64]

    gf_vstats<<<8 * NQ * 16, 256, 0, stream>>>(guide, src, w1, hs);

    gf_solve<<<8 * HLO, 256, 0, stream>>>(hs, ab);

    gf_apply<<<8 * 1024, 256, 0, stream>>>(guide, ab, out);
}